// Round 1
// baseline (90.698 us; speedup 1.0000x reference)
//
#include <hip/hip_runtime.h>
#include <hip/hip_bf16.h>

#define HID 1024
#define NQ 16
#define QD 64
#define MROWS 16384  // B*S = 4*4096

typedef __bf16 bf16;
typedef __bf16 bf16x8 __attribute__((ext_vector_type(8)));
typedef __bf16 bf16x4 __attribute__((ext_vector_type(4)));
typedef float f32x4 __attribute__((ext_vector_type(4)));

// ---------------------------------------------------------------------------
// Kernel 0: fold the 16-point real-FFT cosine matrix into the dense weight,
// store TRANSPOSED as bf16:  Wt[n][q*64+d] = sum_qp cos(2*pi*q*qp/16) * W[qp*64+d][n]
// Thread map: idx = n*64 + d  (d fastest -> coalesced 128B writes per wave per q)
// ---------------------------------------------------------------------------
__global__ __launch_bounds__(256) void wt_k(const float* __restrict__ W,
                                            bf16* __restrict__ Wt) {
    int idx = blockIdx.x * 256 + threadIdx.x;  // 0..65535
    int n = idx >> 6;                           // 0..1023
    int d = idx & 63;

    float w[16];
#pragma unroll
    for (int qp = 0; qp < 16; ++qp)
        w[qp] = W[(size_t)(qp * QD + d) * HID + n];

    // ct[m] = cos(m * pi/8)
    const float ct[16] = {
        1.0f,  0.92387953f,  0.70710678f,  0.38268343f,
        0.0f, -0.38268343f, -0.70710678f, -0.92387953f,
       -1.0f, -0.92387953f, -0.70710678f, -0.38268343f,
        0.0f,  0.38268343f,  0.70710678f,  0.92387953f};

#pragma unroll
    for (int q = 0; q < 16; ++q) {
        float acc = 0.0f;
#pragma unroll
        for (int qp = 0; qp < 16; ++qp)
            acc += w[qp] * ct[(q * qp) & 15];
        Wt[(size_t)n * HID + q * QD + d] = (bf16)acc;
    }
}

// ---------------------------------------------------------------------------
// Kernel 1: LayerNorm + 0.5*sin(2h) -> bf16 A[16384][1024]
// One block (256 threads) per row; float4 loads (4 elems/thread).
// ---------------------------------------------------------------------------
__global__ __launch_bounds__(256) void prep_k(const float* __restrict__ x,
                                              const float* __restrict__ gamma,
                                              const float* __restrict__ beta,
                                              bf16* __restrict__ A) {
    int row = blockIdx.x;
    int t = threadIdx.x;
    const float4* xr = (const float4*)(x + (size_t)row * HID);
    float4 v = xr[t];

    float s  = v.x + v.y + v.z + v.w;
    float ss = v.x * v.x + v.y * v.y + v.z * v.z + v.w * v.w;
#pragma unroll
    for (int off = 32; off; off >>= 1) {
        s  += __shfl_down(s, off);
        ss += __shfl_down(ss, off);
    }
    __shared__ float red[8];
    int wv = t >> 6, ln = t & 63;
    if (ln == 0) { red[wv] = s; red[4 + wv] = ss; }
    __syncthreads();
    float Sm = red[0] + red[1] + red[2] + red[3];
    float Ss = red[4] + red[5] + red[6] + red[7];
    float mean = Sm * (1.0f / HID);
    float var  = Ss * (1.0f / HID) - mean * mean;
    float rstd = rsqrtf(var + 1e-6f);

    float4 g = ((const float4*)gamma)[t];
    float4 b = ((const float4*)beta)[t];

    float h0 = (v.x - mean) * rstd * g.x + b.x;
    float h1 = (v.y - mean) * rstd * g.y + b.y;
    float h2 = (v.z - mean) * rstd * g.z + b.z;
    float h3 = (v.w - mean) * rstd * g.w + b.w;

    bf16x4 o;
    o[0] = (bf16)(0.5f * __sinf(2.0f * h0));
    o[1] = (bf16)(0.5f * __sinf(2.0f * h1));
    o[2] = (bf16)(0.5f * __sinf(2.0f * h2));
    o[3] = (bf16)(0.5f * __sinf(2.0f * h3));
    ((bf16x4*)(A + (size_t)row * HID))[t] = o;
}

// ---------------------------------------------------------------------------
// Kernel 2: GEMM  C[m][n] = sum_k A[m][k]*Wt[n][k] + bias[n]
// m97 structure: 128x128 tile, BK=32, 4 waves (2x2), 4x4 16x16x32 MFMA frags,
// global_load_lds width 16, double-buffered 2-phase.
// ---------------------------------------------------------------------------
#define BM 128
#define BN 128
#define BK 32

__global__ __launch_bounds__(256) void gemm_k(const bf16* __restrict__ A,
                                              const bf16* __restrict__ Bt,
                                              const float* __restrict__ bias,
                                              float* __restrict__ C) {
    constexpr int K = HID, N = HID;
    __shared__ __attribute__((aligned(16))) bf16 sA[2][BM * BK];
    __shared__ __attribute__((aligned(16))) bf16 sB[2][BN * BK];

    int bid = blockIdx.x;
    int bn = bid & 7;   // N/BN = 8
    int bm = bid >> 3;  // 0..127

    int t = threadIdx.x;
    int wv = t >> 6, ln = t & 63;
    int wr = wv >> 1, wc = wv & 1;    // wave 64x64 sub-tile
    int fr = ln & 15, fq = ln >> 4;   // fragment lane decomposition

    auto stage = [&](int buf, int kt) {
#pragma unroll
        for (int c = 0; c < 2; ++c) {
            int ch = c * 4 + wv;         // 0..7 wave-chunks of 1024B
            int e0 = ch * 512;           // chunk start element
            int e  = e0 + ln * 8;        // this lane's 8 source elements
            int row = e >> 5, col = e & 31;
            const bf16* ga = A + (size_t)(bm * BM + row) * K + kt * BK + col;
            __builtin_amdgcn_global_load_lds(
                (const __attribute__((address_space(1))) void*)ga,
                (__attribute__((address_space(3))) void*)&sA[buf][e0], 16, 0, 0);
            const bf16* gb = Bt + (size_t)(bn * BN + row) * K + kt * BK + col;
            __builtin_amdgcn_global_load_lds(
                (const __attribute__((address_space(1))) void*)gb,
                (__attribute__((address_space(3))) void*)&sB[buf][e0], 16, 0, 0);
        }
    };

    f32x4 acc[4][4];
#pragma unroll
    for (int i = 0; i < 4; ++i)
#pragma unroll
        for (int j = 0; j < 4; ++j)
            acc[i][j] = (f32x4){0.f, 0.f, 0.f, 0.f};

    stage(0, 0);
    __syncthreads();
    int cur = 0;
#pragma unroll 1
    for (int kt = 0; kt < K / BK; ++kt) {
        if (kt + 1 < K / BK) stage(cur ^ 1, kt + 1);

        bf16x8 af[4], bfr[4];
#pragma unroll
        for (int i = 0; i < 4; ++i)
            af[i] = *(const bf16x8*)&sA[cur][(wr * 64 + i * 16 + fr) * BK + fq * 8];
#pragma unroll
        for (int j = 0; j < 4; ++j)
            bfr[j] = *(const bf16x8*)&sB[cur][(wc * 64 + j * 16 + fr) * BK + fq * 8];
#pragma unroll
        for (int i = 0; i < 4; ++i)
#pragma unroll
            for (int j = 0; j < 4; ++j)
                acc[i][j] = __builtin_amdgcn_mfma_f32_16x16x32_bf16(af[i], bfr[j], acc[i][j], 0, 0, 0);

        __syncthreads();
        cur ^= 1;
    }

    // Epilogue: C/D layout col = lane&15, row = (lane>>4)*4 + reg
#pragma unroll
    for (int j = 0; j < 4; ++j) {
        int cn = bn * BN + wc * 64 + j * 16 + fr;
        float bv = bias[cn];
#pragma unroll
        for (int i = 0; i < 4; ++i) {
            int r0 = bm * BM + wr * 64 + i * 16 + fq * 4;
#pragma unroll
            for (int jj = 0; jj < 4; ++jj)
                C[(size_t)(r0 + jj) * N + cn] = acc[i][j][jj] + bv;
        }
    }
}

// ---------------------------------------------------------------------------
extern "C" void kernel_launch(void* const* d_in, const int* in_sizes, int n_in,
                              void* d_out, int out_size, void* d_ws, size_t ws_size,
                              hipStream_t stream) {
    const float* x     = (const float*)d_in[0];
    const float* lng   = (const float*)d_in[1];
    const float* lnb   = (const float*)d_in[2];
    const float* W     = (const float*)d_in[3];
    const float* db    = (const float*)d_in[4];
    float* out = (float*)d_out;

    bf16* A  = (bf16*)d_ws;                                        // 32 MB
    bf16* Wt = (bf16*)((char*)d_ws + (size_t)MROWS * HID * 2);     // 2 MB

    wt_k<<<(HID * QD) / 256, 256, 0, stream>>>(W, Wt);
    prep_k<<<MROWS, 256, 0, stream>>>(x, lng, lnb, A);
    gemm_k<<<(MROWS / BM) * (HID / BN), 256, 0, stream>>>(A, Wt, db, out);
}

// Round 2
// 71.698 us; speedup vs baseline: 1.2650x; 1.2650x over previous
//
#include <hip/hip_runtime.h>
#include <hip/hip_bf16.h>

#define HID 1024
#define NQ 16
#define QD 64
#define MROWS 16384  // B*S = 4*4096

typedef __bf16 bf16;
typedef __bf16 bf16x8 __attribute__((ext_vector_type(8)));
typedef __bf16 bf16x4 __attribute__((ext_vector_type(4)));
typedef float f32x4 __attribute__((ext_vector_type(4)));

// ---------------------------------------------------------------------------
// Kernel 0: fold the 16-point real-FFT cosine matrix into the dense weight,
// store TRANSPOSED as bf16:  Wt[n][q*64+d] = sum_qp cos(2*pi*q*qp/16) * W[qp*64+d][n]
// ---------------------------------------------------------------------------
__global__ __launch_bounds__(256) void wt_k(const float* __restrict__ W,
                                            bf16* __restrict__ Wt) {
    int idx = blockIdx.x * 256 + threadIdx.x;  // 0..65535
    int n = idx >> 6;
    int d = idx & 63;

    float w[16];
#pragma unroll
    for (int qp = 0; qp < 16; ++qp)
        w[qp] = W[(size_t)(qp * QD + d) * HID + n];

    const float ct[16] = {
        1.0f,  0.92387953f,  0.70710678f,  0.38268343f,
        0.0f, -0.38268343f, -0.70710678f, -0.92387953f,
       -1.0f, -0.92387953f, -0.70710678f, -0.38268343f,
        0.0f,  0.38268343f,  0.70710678f,  0.92387953f};

#pragma unroll
    for (int q = 0; q < 16; ++q) {
        float acc = 0.0f;
#pragma unroll
        for (int qp = 0; qp < 16; ++qp)
            acc += w[qp] * ct[(q * qp) & 15];
        Wt[(size_t)n * HID + q * QD + d] = (bf16)acc;
    }
}

// ---------------------------------------------------------------------------
// Kernel 1: LayerNorm + 0.5*sin(2h) -> bf16 A[16384][1024]
// ---------------------------------------------------------------------------
__global__ __launch_bounds__(256) void prep_k(const float* __restrict__ x,
                                              const float* __restrict__ gamma,
                                              const float* __restrict__ beta,
                                              bf16* __restrict__ A) {
    int row = blockIdx.x;
    int t = threadIdx.x;
    const float4* xr = (const float4*)(x + (size_t)row * HID);
    float4 v = xr[t];

    float s  = v.x + v.y + v.z + v.w;
    float ss = v.x * v.x + v.y * v.y + v.z * v.z + v.w * v.w;
#pragma unroll
    for (int off = 32; off; off >>= 1) {
        s  += __shfl_down(s, off);
        ss += __shfl_down(ss, off);
    }
    __shared__ float red[8];
    int wv = t >> 6, ln = t & 63;
    if (ln == 0) { red[wv] = s; red[4 + wv] = ss; }
    __syncthreads();
    float Sm = red[0] + red[1] + red[2] + red[3];
    float Ss = red[4] + red[5] + red[6] + red[7];
    float mean = Sm * (1.0f / HID);
    float var  = Ss * (1.0f / HID) - mean * mean;
    float rstd = rsqrtf(var + 1e-6f);

    float4 g = ((const float4*)gamma)[t];
    float4 b = ((const float4*)beta)[t];

    float h0 = (v.x - mean) * rstd * g.x + b.x;
    float h1 = (v.y - mean) * rstd * g.y + b.y;
    float h2 = (v.z - mean) * rstd * g.z + b.z;
    float h3 = (v.w - mean) * rstd * g.w + b.w;

    bf16x4 o;
    o[0] = (bf16)(0.5f * __sinf(2.0f * h0));
    o[1] = (bf16)(0.5f * __sinf(2.0f * h1));
    o[2] = (bf16)(0.5f * __sinf(2.0f * h2));
    o[3] = (bf16)(0.5f * __sinf(2.0f * h3));
    ((bf16x4*)(A + (size_t)row * HID))[t] = o;
}

// ---------------------------------------------------------------------------
// Kernel 2: 256x256 8-phase GEMM  C[m][n] = sum_k A[m][k]*Wt[n][k] + bias[n]
// 8 waves (2M x 4N), BK=64, double-buffered 128 KiB LDS, counted vmcnt,
// XOR-swizzled LDS (inverse-swizzled global source + swizzled ds_read).
// ---------------------------------------------------------------------------
#define BM 256
#define BN 256
#define BK 64
#define NT (HID / BK)  // 16 K-tiles

#define MFMA(va, vb, vc) __builtin_amdgcn_mfma_f32_16x16x32_bf16(va, vb, vc, 0, 0, 0)

__global__ __launch_bounds__(512, 2) void gemm_k(const bf16* __restrict__ A,
                                                 const bf16* __restrict__ Bt,
                                                 const float* __restrict__ bias,
                                                 float* __restrict__ C) {
    // LDS: [buf(2)][mat(2): A,B][row 256][64 bf16] = 131072 B
    __shared__ __attribute__((aligned(16))) char lds[131072];

    const int tid = threadIdx.x;
    const int w = tid >> 6, ln = tid & 63;
    const int wm = w >> 2, wn = w & 3;
    const int fr = ln & 15, fq = ln >> 4;

    // XCD-chunked bijective swizzle (grid=256, 256%8==0)
    int orig = blockIdx.x;
    int wg = (orig & 7) * 32 + (orig >> 3);
    int bm = wg >> 2, bn = wg & 3;  // 64 x 4 tiles

    const bf16* Ab = A + (size_t)bm * BM * HID;
    const bf16* Bb = Bt + (size_t)bn * BN * HID;

    // stage one half-tile (128 rows x 64 cols) of mat {0=A,1=B}, rows [R0,R0+128),
    // K-tile kt, into buffer buf.  LDS dest linear; source pre-swizzled so that
    // physical LDS ends up XOR-swizzled: phys = linear ^ ((row&7)<<4).
    auto stage = [&](int buf, int mat, int R0, int kt) {
        const char* gsrc = (const char*)(mat ? Bb : Ab);
        char* base = lds + (((buf << 1) | mat) << 15) + (R0 << 7);
        const int kb = kt << 7;  // kt * 64 cols * 2B
#pragma unroll
        for (int l = 0; l < 2; ++l) {
            int c = (l << 9) + tid;              // chunk 0..1023 (16B each)
            int lr = c >> 3;                     // local row 0..127
            int colB = ((c & 7) ^ (lr & 7)) << 4;  // inverse-swizzled source col
            const char* g = gsrc + (size_t)(R0 + lr) * (HID * 2) + kb + colB;
            __builtin_amdgcn_global_load_lds(
                (const __attribute__((address_space(1))) void*)g,
                (__attribute__((address_space(3))) void*)(base + (((l << 9) + (w << 6)) << 4)),
                16, 0, 0);
        }
    };

    // swizzled fragment reads. A-frag i: rows (i*2+wm)*16+fr; B-frag j: rows (j*4+wn)*16+fr
    auto readA = [&](int buf, int i, int ks) -> bf16x8 {
        int r = ((i * 2 + wm) << 4) + fr;
        int off = (r << 7) + (ks << 6) + (fq << 4);
        off ^= (fr & 7) << 4;
        return *(const bf16x8*)(lds + ((buf << 1) << 15) + off);
    };
    auto readB = [&](int buf, int j, int ks) -> bf16x8 {
        int r = ((j * 4 + wn) << 4) + fr;
        int off = (r << 7) + (ks << 6) + (fq << 4);
        off ^= (fr & 7) << 4;
        return *(const bf16x8*)(lds + (((buf << 1) | 1) << 15) + off);
    };

    f32x4 acc[8][4];
#pragma unroll
    for (int i = 0; i < 8; ++i)
#pragma unroll
        for (int j = 0; j < 4; ++j) acc[i][j] = (f32x4){0.f, 0.f, 0.f, 0.f};

    // Prologue: issue order must match steady-state stream:
    // Blo(0), Ahi(0), Alo(0), Bhi(0), Blo(1), Ahi(1)  -> wait all of tile 0 (4 left)
    stage(0, 1, 0, 0);
    stage(0, 0, 128, 0);
    stage(0, 0, 0, 0);
    stage(0, 1, 128, 0);
    stage(1, 1, 0, 1);
    stage(1, 0, 128, 1);
    asm volatile("s_waitcnt vmcnt(4)" ::: "memory");
    __builtin_amdgcn_s_barrier();

    bf16x8 a[8][2], b[4][2];

#pragma unroll 1
    for (int t = 0; t < NT; ++t) {
        const int cur = t & 1, nxt = cur ^ 1;

        // ---- P0: ds_read Alo frags + Blo frags; stage Alo(t+1); MFMA m0-3 x n0-1
#pragma unroll
        for (int i = 0; i < 4; ++i) { a[i][0] = readA(cur, i, 0); a[i][1] = readA(cur, i, 1); }
#pragma unroll
        for (int j = 0; j < 2; ++j) { b[j][0] = readB(cur, j, 0); b[j][1] = readB(cur, j, 1); }
        if (t + 1 < NT) stage(nxt, 0, 0, t + 1);
        __builtin_amdgcn_s_barrier();
        asm volatile("s_waitcnt lgkmcnt(0)" ::: "memory");
        __builtin_amdgcn_sched_barrier(0);
        __builtin_amdgcn_s_setprio(1);
#pragma unroll
        for (int i = 0; i < 4; ++i)
#pragma unroll
            for (int j = 0; j < 2; ++j) {
                acc[i][j] = MFMA(a[i][0], b[j][0], acc[i][j]);
                acc[i][j] = MFMA(a[i][1], b[j][1], acc[i][j]);
            }
        __builtin_amdgcn_s_setprio(0);
        __builtin_amdgcn_s_barrier();

        // ---- P1: ds_read Ahi frags; stage Bhi(t+1); MFMA m4-7 x n0-1
#pragma unroll
        for (int i = 4; i < 8; ++i) { a[i][0] = readA(cur, i, 0); a[i][1] = readA(cur, i, 1); }
        if (t + 1 < NT) stage(nxt, 1, 128, t + 1);
        __builtin_amdgcn_s_barrier();
        asm volatile("s_waitcnt lgkmcnt(0)" ::: "memory");
        __builtin_amdgcn_sched_barrier(0);
        __builtin_amdgcn_s_setprio(1);
#pragma unroll
        for (int i = 4; i < 8; ++i)
#pragma unroll
            for (int j = 0; j < 2; ++j) {
                acc[i][j] = MFMA(a[i][0], b[j][0], acc[i][j]);
                acc[i][j] = MFMA(a[i][1], b[j][1], acc[i][j]);
            }
        __builtin_amdgcn_s_setprio(0);
        __builtin_amdgcn_s_barrier();

        // ---- P2: ds_read Bhi frags; stage Blo(t+2) (into cur: Blo reads done at P0); MFMA m4-7 x n2-3
#pragma unroll
        for (int j = 2; j < 4; ++j) { b[j][0] = readB(cur, j, 0); b[j][1] = readB(cur, j, 1); }
        if (t + 2 < NT) stage(cur, 1, 0, t + 2);
        __builtin_amdgcn_s_barrier();
        asm volatile("s_waitcnt lgkmcnt(0)" ::: "memory");
        __builtin_amdgcn_sched_barrier(0);
        __builtin_amdgcn_s_setprio(1);
#pragma unroll
        for (int i = 4; i < 8; ++i)
#pragma unroll
            for (int j = 2; j < 4; ++j) {
                acc[i][j] = MFMA(a[i][0], b[j][0], acc[i][j]);
                acc[i][j] = MFMA(a[i][1], b[j][1], acc[i][j]);
            }
        __builtin_amdgcn_s_setprio(0);
        __builtin_amdgcn_s_barrier();

        // ---- P3: stage Ahi(t+2) (Ahi reads done at P1); MFMA m0-3 x n2-3; counted vmcnt
        if (t + 2 < NT) stage(cur, 0, 128, t + 2);
        __builtin_amdgcn_s_barrier();
        __builtin_amdgcn_s_setprio(1);
#pragma unroll
        for (int i = 0; i < 4; ++i)
#pragma unroll
            for (int j = 2; j < 4; ++j) {
                acc[i][j] = MFMA(a[i][0], b[j][0], acc[i][j]);
                acc[i][j] = MFMA(a[i][1], b[j][1], acc[i][j]);
            }
        __builtin_amdgcn_s_setprio(0);
        // wait: all 4 halves of tile t+1 landed; leave tile t+2's (if staged) in flight
        if (t + 2 < NT) {
            asm volatile("s_waitcnt vmcnt(4)" ::: "memory");
        } else if (t + 1 < NT) {
            asm volatile("s_waitcnt vmcnt(0)" ::: "memory");
        }
        __builtin_amdgcn_sched_barrier(0);
        __builtin_amdgcn_s_barrier();
    }

    // Epilogue: C/D layout col = lane&15, row = (lane>>4)*4 + reg
#pragma unroll
    for (int j = 0; j < 4; ++j) {
        int col = bn * BN + ((j * 4 + wn) << 4) + fr;
        float bv = bias[col];
#pragma unroll
        for (int i = 0; i < 8; ++i) {
            int row0 = bm * BM + ((i * 2 + wm) << 4) + (fq << 2);
#pragma unroll
            for (int jj = 0; jj < 4; ++jj)
                C[(size_t)(row0 + jj) * HID + col] = acc[i][j][jj] + bv;
        }
    }
}

// ---------------------------------------------------------------------------
extern "C" void kernel_launch(void* const* d_in, const int* in_sizes, int n_in,
                              void* d_out, int out_size, void* d_ws, size_t ws_size,
                              hipStream_t stream) {
    const float* x   = (const float*)d_in[0];
    const float* lng = (const float*)d_in[1];
    const float* lnb = (const float*)d_in[2];
    const float* W   = (const float*)d_in[3];
    const float* db  = (const float*)d_in[4];
    float* out = (float*)d_out;

    bf16* A  = (bf16*)d_ws;                                     // 32 MB
    bf16* Wt = (bf16*)((char*)d_ws + (size_t)MROWS * HID * 2);  // 2 MB

    wt_k<<<(HID * QD) / 256, 256, 0, stream>>>(W, Wt);
    prep_k<<<MROWS, 256, 0, stream>>>(x, lng, lnb, A);
    gemm_k<<<(MROWS / BM) * (HID / BN), 512, 0, stream>>>(A, Wt, db, out);
}